// Round 7
// baseline (800.812 us; speedup 1.0000x reference)
//
#include <hip/hip_runtime.h>

#define BATCH 4
#define CCH   64
#define NPIX  4096
#define KD    32
#define OD    64
#define KK    409       // N / TOPK
#define EPSF  1e-10f

// ---------------------------------------------------------------------------
// Kernel A: per-pixel linear projections (1x1 convs).  (unchanged)
// ---------------------------------------------------------------------------
__global__ __launch_bounds__(256) void qkv_kernel(
    const float* __restrict__ x,
    const float* __restrict__ Wq, const float* __restrict__ bq,
    const float* __restrict__ Wk, const float* __restrict__ bk,
    const float* __restrict__ Wv, const float* __restrict__ bv,
    float* __restrict__ Q, float* __restrict__ Km, float* __restrict__ Vm)
{
    __shared__ float xt[64][65];
    __shared__ float wq_s[KD * 64];
    __shared__ float wk_s[KD * 64];
    __shared__ float wv_s[OD * 64];
    __shared__ float bq_s[KD], bk_s[KD], bv_s[OD];

    int tid = threadIdx.x;
    int bx  = blockIdx.x;
    int b   = bx >> 6;
    int n0  = (bx & 63) << 6;

    for (int i = tid; i < KD * 64; i += 256) { wq_s[i] = Wq[i]; wk_s[i] = Wk[i]; }
    for (int i = tid; i < OD * 64; i += 256) wv_s[i] = Wv[i];
    if (tid < KD) { bq_s[tid] = bq[tid]; bk_s[tid] = bk[tid]; }
    if (tid < OD) bv_s[tid] = bv[tid];
    for (int i = tid; i < 64 * 64; i += 256) {
        int c = i >> 6, p = i & 63;
        xt[c][p] = x[((size_t)b * CCH + c) * NPIX + n0 + p];
    }
    __syncthreads();

    int px  = tid & 63;
    int grp = tid >> 6;
    int n   = n0 + px;

    if (grp == 0) {
        for (int o = 0; o < KD; ++o) {
            float acc = bq_s[o];
            #pragma unroll
            for (int c = 0; c < 64; ++c) acc += wq_s[o * 64 + c] * xt[c][px];
            Q[((size_t)b * NPIX + n) * KD + o] = acc;
        }
    } else if (grp == 1) {
        for (int o = 0; o < KD; ++o) {
            float acc = bk_s[o];
            #pragma unroll
            for (int c = 0; c < 64; ++c) acc += wk_s[o * 64 + c] * xt[c][px];
            Km[((size_t)b * KD + o) * NPIX + n] = acc;
        }
    } else {
        int obase = (grp - 2) * 32;
        for (int oo = 0; oo < 32; ++oo) {
            int o = obase + oo;
            float acc = bv_s[o];
            #pragma unroll
            for (int c = 0; c < 64; ++c) acc += wv_s[o * 64 + c] * xt[c][px];
            Vm[((size_t)b * NPIX + n) * OD + o] = acc;
        }
    }
}

// ---------------------------------------------------------------------------
// Kernel B: one block = 4 consecutive rows; K loads amortized 4x.
// After one barrier, wave w owns row w end-to-end (own hist/scan/selection/PV)
// -> no further barriers, register-based compaction, no selection atomics.
// ---------------------------------------------------------------------------
__global__ __launch_bounds__(256) void attn_kernel(
    const float* __restrict__ x,  const float* __restrict__ Q,
    const float* __restrict__ Km, const float* __restrict__ Vm,
    const float* __restrict__ gamma, float* __restrict__ out)
{
    __shared__ __align__(16) unsigned short ek[4][NPIX];   // 32 KB keys
    __shared__ __align__(16) float qld[KD][4];             // q transposed
    __shared__ __align__(16) unsigned h4[4][256];          // per-wave hist
    __shared__ unsigned selbuf[4][KK + 7];                 // (j<<16)|key
    __shared__ unsigned redk0[4][4];                       // [wv][row]
    volatile __shared__ unsigned sh_b4[4], sh_r4[4];

    int tid  = threadIdx.x;
    int lane = tid & 63, wv = tid >> 6;
    int bx   = blockIdx.x;
    int b    = bx >> 10;             // 1024 blocks per batch
    int i0   = (bx & 1023) << 2;     // 4 rows per block

    float gscale = gamma[0];

    if (tid < 128) {
        int kd = tid & 31, rr = tid >> 5;
        qld[kd][rr] = Q[((size_t)b * NPIX + i0 + rr) * KD + kd];
    }
    __syncthreads();                                        // B0: q ready

    // key map (m-independent): k = clamp((int)fma(e, 4096, 32768), 0, 65535)
    #define EKEY(EV, KV) { KV = (int)fmaf((EV), 4096.0f, 32768.0f); \
                           KV = KV < 0 ? 0 : (KV > 65535 ? 65535 : KV); }

    // ---- energy: 4 rows x 16 cols per thread; K float4 shared by 4 rows ----
    const float4* Kb4 = (const float4*)(Km + (size_t)b * KD * NPIX);
    unsigned lmax0 = 0u, lmax1 = 0u, lmax2 = 0u, lmax3 = 0u;
    #pragma unroll
    for (int g = 0; g < 4; ++g) {
        int c4 = tid + (g << 8);
        float4 a0 = {0,0,0,0}, a1 = {0,0,0,0}, a2 = {0,0,0,0}, a3 = {0,0,0,0};
        #pragma unroll
        for (int kd = 0; kd < KD; ++kd) {
            float4 kv = Kb4[(kd << 10) + c4];
            float4 qv = *(const float4*)qld[kd];            // broadcast b128
            a0.x = fmaf(qv.x, kv.x, a0.x); a0.y = fmaf(qv.x, kv.y, a0.y);
            a0.z = fmaf(qv.x, kv.z, a0.z); a0.w = fmaf(qv.x, kv.w, a0.w);
            a1.x = fmaf(qv.y, kv.x, a1.x); a1.y = fmaf(qv.y, kv.y, a1.y);
            a1.z = fmaf(qv.y, kv.z, a1.z); a1.w = fmaf(qv.y, kv.w, a1.w);
            a2.x = fmaf(qv.z, kv.x, a2.x); a2.y = fmaf(qv.z, kv.y, a2.y);
            a2.z = fmaf(qv.z, kv.z, a2.z); a2.w = fmaf(qv.z, kv.w, a2.w);
            a3.x = fmaf(qv.w, kv.x, a3.x); a3.y = fmaf(qv.w, kv.y, a3.y);
            a3.z = fmaf(qv.w, kv.z, a3.z); a3.w = fmaf(qv.w, kv.w, a3.w);
        }
        #define DOROW(A, R, LM) { int k0,k1,k2,k3; \
            EKEY(A.x,k0); EKEY(A.y,k1); EKEY(A.z,k2); EKEY(A.w,k3); \
            LM = max(LM, (unsigned)max(max(k0,k1),max(k2,k3))); \
            ((ushort4*)ek[R])[c4] = make_ushort4((unsigned short)k0,(unsigned short)k1, \
                                                 (unsigned short)k2,(unsigned short)k3); }
        DOROW(a0, 0, lmax0) DOROW(a1, 1, lmax1) DOROW(a2, 2, lmax2) DOROW(a3, 3, lmax3)
        #undef DOROW
    }
    #define RMAX(V, R) { unsigned v_ = (V); \
        _Pragma("unroll") \
        for (int off = 32; off; off >>= 1) \
            v_ = max(v_, (unsigned)__shfl_down((int)v_, off, 64)); \
        if (lane == 0) redk0[wv][R] = v_; }
    RMAX(lmax0, 0) RMAX(lmax1, 1) RMAX(lmax2, 2) RMAX(lmax3, 3)
    #undef RMAX
    __syncthreads();                                        // B1: keys + maxes

    // ================= per-wave from here: wave wv owns row i0+wv ==========
    const int r = wv;
    const int i = i0 + r;
    unsigned mk = max(max(redk0[0][r], redk0[1][r]), max(redk0[2][r], redk0[3][r]));
    const ushort4* ek4 = (const ushort4*)ek[r];
    unsigned* hw = h4[r];

    // wave suffix-scan over own 256-bin hist; result via own LDS slot
    #define WSCAN(RNEED, OUTB, OUTR) { \
        uint4 hh = *((const uint4*)&hw[lane << 2]); \
        unsigned s3 = hh.w, s2 = hh.w + hh.z, s1 = s2 + hh.y, s0 = s1 + hh.x; \
        unsigned X = s0; \
        _Pragma("unroll") \
        for (int off = 1; off < 64; off <<= 1) { \
            unsigned v = (unsigned)__shfl_down((int)X, off, 64); \
            if (lane + off < 64) X += v; } \
        unsigned Xn = (unsigned)__shfl_down((int)X, 1, 64); \
        if (lane == 63) Xn = 0u; \
        unsigned S0 = X, S1 = Xn + s1, S2 = Xn + s2, S3 = Xn + s3, S4 = Xn; \
        if (S0 >= (RNEED) && S1 < (RNEED)) { sh_b4[r] = (lane << 2) | 0; sh_r4[r] = (RNEED) - S1; } \
        if (S1 >= (RNEED) && S2 < (RNEED)) { sh_b4[r] = (lane << 2) | 1; sh_r4[r] = (RNEED) - S2; } \
        if (S2 >= (RNEED) && S3 < (RNEED)) { sh_b4[r] = (lane << 2) | 2; sh_r4[r] = (RNEED) - S3; } \
        if (S3 >= (RNEED) && S4 < (RNEED)) { sh_b4[r] = (lane << 2) | 3; sh_r4[r] = (RNEED) - S4; } \
        OUTB = sh_b4[r]; OUTR = sh_r4[r]; }

    // ---- pass A: hist on high byte ----
    #pragma unroll
    for (int z = 0; z < 4; ++z) hw[(z << 6) + lane] = 0u;
    #pragma unroll
    for (int g = 0; g < 16; ++g) {
        ushort4 kv = ek4[lane + (g << 6)];
        atomicAdd(&hw[kv.x >> 8], 1u);
        atomicAdd(&hw[kv.y >> 8], 1u);
        atomicAdd(&hw[kv.z >> 8], 1u);
        atomicAdd(&hw[kv.w >> 8], 1u);
    }
    unsigned bh, rn;
    WSCAN(KK, bh, rn)

    // ---- pass B: hist on low byte within selected high-byte bin ----
    #pragma unroll
    for (int z = 0; z < 4; ++z) hw[(z << 6) + lane] = 0u;
    #pragma unroll
    for (int g = 0; g < 16; ++g) {
        ushort4 kv = ek4[lane + (g << 6)];
        if ((unsigned)(kv.x >> 8) == bh) atomicAdd(&hw[kv.x & 255u], 1u);
        if ((unsigned)(kv.y >> 8) == bh) atomicAdd(&hw[kv.y & 255u], 1u);
        if ((unsigned)(kv.z >> 8) == bh) atomicAdd(&hw[kv.z & 255u], 1u);
        if ((unsigned)(kv.w >> 8) == bh) atomicAdd(&hw[kv.w & 255u], 1u);
    }
    unsigned bl, rt;
    WSCAN(rn, bl, rt)
    #undef WSCAN
    int tu = (int)((bh << 8) | bl);

    // ---- selection: register-based compaction (no atomics) ----
    unsigned base = 0u, tbase = 0u;
    float lsum = 0.f;
    #pragma unroll
    for (int g = 0; g < 16; ++g) {
        ushort4 kv = ek4[lane + (g << 6)];
        #pragma unroll
        for (int c = 0; c < 4; ++c) {
            int k = (c == 0) ? kv.x : (c == 1) ? kv.y : (c == 2) ? kv.z : kv.w;
            bool tie = (k == tu);
            unsigned long long tmask = __ballot(tie);
            bool sel = (k > tu);
            if (tie) {
                unsigned tix = tbase + (unsigned)__popcll(tmask & ((1ull << lane) - 1ull));
                sel = (tix < rt);
            }
            tbase += (unsigned)__popcll(tmask);
            unsigned long long smask = __ballot(sel);
            if (sel) {
                unsigned pos = base + (unsigned)__popcll(smask & ((1ull << lane) - 1ull));
                int j = ((lane + (g << 6)) << 2) | c;
                selbuf[r][pos] = ((unsigned)j << 16) | (unsigned)k;
                lsum += __expf((float)(k - (int)mk) * 0.000244140625f);
            }
            base += (unsigned)__popcll(smask);
        }
    }
    #pragma unroll
    for (int off = 32; off; off >>= 1) lsum += __shfl_xor(lsum, off, 64);
    float denom = lsum + EPSF;

    // ---- PV gather: 4 entries x 16 lanes x float4, one wave per row ----
    int eslot = lane >> 4, vq = lane & 15;
    const float4* Vb4 = (const float4*)(Vm + (size_t)b * NPIX * OD);
    const unsigned* selr = selbuf[r];
    float4 acc = make_float4(0.f, 0.f, 0.f, 0.f);
    for (int s0 = 0; s0 < KK; s0 += 4) {
        int s = s0 + eslot;
        if (s < KK) {
            unsigned pk = selr[s];
            float w = __expf((float)((int)(pk & 0xFFFFu) - (int)mk) * 0.000244140625f);
            float4 v4 = Vb4[(((int)(pk >> 16)) << 4) + vq];
            acc.x = fmaf(w, v4.x, acc.x);
            acc.y = fmaf(w, v4.y, acc.y);
            acc.z = fmaf(w, v4.z, acc.z);
            acc.w = fmaf(w, v4.w, acc.w);
        }
    }
    #pragma unroll
    for (int off = 16; off <= 32; off <<= 1) {
        acc.x += __shfl_xor(acc.x, off, 64);
        acc.y += __shfl_xor(acc.y, off, 64);
        acc.z += __shfl_xor(acc.z, off, 64);
        acc.w += __shfl_xor(acc.w, off, 64);
    }
    if (lane < 16) {
        float sc = gscale / denom;
        size_t basei = ((size_t)b * CCH + (vq << 2)) * NPIX + i;
        out[basei]            = fmaf(sc, acc.x, x[basei]);
        out[basei +   NPIX]   = fmaf(sc, acc.y, x[basei +   NPIX]);
        out[basei + 2*NPIX]   = fmaf(sc, acc.z, x[basei + 2*NPIX]);
        out[basei + 3*NPIX]   = fmaf(sc, acc.w, x[basei + 3*NPIX]);
    }
}

extern "C" void kernel_launch(void* const* d_in, const int* in_sizes, int n_in,
                              void* d_out, int out_size, void* d_ws, size_t ws_size,
                              hipStream_t stream) {
    const float* x     = (const float*)d_in[0];
    const float* Wq    = (const float*)d_in[1];
    const float* bq    = (const float*)d_in[2];
    const float* Wk    = (const float*)d_in[3];
    const float* bk    = (const float*)d_in[4];
    const float* Wv    = (const float*)d_in[5];
    const float* bv    = (const float*)d_in[6];
    const float* gamma = (const float*)d_in[7];
    float* out = (float*)d_out;

    float* Q  = (float*)d_ws;
    float* Km = Q  + (size_t)BATCH * NPIX * KD;
    float* Vm = Km + (size_t)BATCH * KD * NPIX;

    qkv_kernel<<<BATCH * (NPIX / 64), 256, 0, stream>>>(x, Wq, bq, Wk, bk, Wv, bv, Q, Km, Vm);
    attn_kernel<<<BATCH * (NPIX / 4), 256, 0, stream>>>(x, Q, Km, Vm, gamma, out);
}

// Round 8
// 385.616 us; speedup vs baseline: 2.0767x; 2.0767x over previous
//
#include <hip/hip_runtime.h>

#define BATCH 4
#define CCH   64
#define NPIX  4096
#define KD    32
#define OD    64
#define KK    409       // N / TOPK
#define EPSF  1e-10f

// ---------------------------------------------------------------------------
// Kernel A: per-pixel linear projections (1x1 convs).  (unchanged)
// ---------------------------------------------------------------------------
__global__ __launch_bounds__(256) void qkv_kernel(
    const float* __restrict__ x,
    const float* __restrict__ Wq, const float* __restrict__ bq,
    const float* __restrict__ Wk, const float* __restrict__ bk,
    const float* __restrict__ Wv, const float* __restrict__ bv,
    float* __restrict__ Q, float* __restrict__ Km, float* __restrict__ Vm)
{
    __shared__ float xt[64][65];
    __shared__ float wq_s[KD * 64];
    __shared__ float wk_s[KD * 64];
    __shared__ float wv_s[OD * 64];
    __shared__ float bq_s[KD], bk_s[KD], bv_s[OD];

    int tid = threadIdx.x;
    int bx  = blockIdx.x;
    int b   = bx >> 6;
    int n0  = (bx & 63) << 6;

    for (int i = tid; i < KD * 64; i += 256) { wq_s[i] = Wq[i]; wk_s[i] = Wk[i]; }
    for (int i = tid; i < OD * 64; i += 256) wv_s[i] = Wv[i];
    if (tid < KD) { bq_s[tid] = bq[tid]; bk_s[tid] = bk[tid]; }
    if (tid < OD) bv_s[tid] = bv[tid];
    for (int i = tid; i < 64 * 64; i += 256) {
        int c = i >> 6, p = i & 63;
        xt[c][p] = x[((size_t)b * CCH + c) * NPIX + n0 + p];
    }
    __syncthreads();

    int px  = tid & 63;
    int grp = tid >> 6;
    int n   = n0 + px;

    if (grp == 0) {
        for (int o = 0; o < KD; ++o) {
            float acc = bq_s[o];
            #pragma unroll
            for (int c = 0; c < 64; ++c) acc += wq_s[o * 64 + c] * xt[c][px];
            Q[((size_t)b * NPIX + n) * KD + o] = acc;
        }
    } else if (grp == 1) {
        for (int o = 0; o < KD; ++o) {
            float acc = bk_s[o];
            #pragma unroll
            for (int c = 0; c < 64; ++c) acc += wk_s[o * 64 + c] * xt[c][px];
            Km[((size_t)b * KD + o) * NPIX + n] = acc;
        }
    } else {
        int obase = (grp - 2) * 32;
        for (int oo = 0; oo < 32; ++oo) {
            int o = obase + oo;
            float acc = bv_s[o];
            #pragma unroll
            for (int c = 0; c < 64; ++c) acc += wv_s[o * 64 + c] * xt[c][px];
            Vm[((size_t)b * NPIX + n) * OD + o] = acc;
        }
    }
}

// ---------------------------------------------------------------------------
// Kernel B: one block = 4 consecutive rows; K loads amortized 4x.
// Register-pressure-controlled: outer energy loop NOT unrolled (one
// g-iteration's 16 accumulators live), kd loop unroll 4, hard VGPR cap 128.
// After one barrier, wave w owns row w end-to-end.
// ---------------------------------------------------------------------------
__global__ __launch_bounds__(256, 2) void attn_kernel(
    const float* __restrict__ x,  const float* __restrict__ Q,
    const float* __restrict__ Km, const float* __restrict__ Vm,
    const float* __restrict__ gamma, float* __restrict__ out)
{
    __shared__ __align__(16) unsigned short ek[4][NPIX];   // 32 KB keys
    __shared__ __align__(16) float qld[KD][4];             // q transposed
    __shared__ __align__(16) unsigned h4[4][256];          // per-wave hist
    __shared__ unsigned selbuf[4][KK + 7];                 // (j<<16)|key
    __shared__ unsigned redk0[4][4];                       // [wv][row]
    volatile __shared__ unsigned sh_b4[4], sh_r4[4];

    int tid  = threadIdx.x;
    int lane = tid & 63, wv = tid >> 6;
    int bx   = blockIdx.x;
    int b    = bx >> 10;             // 1024 blocks per batch
    int i0   = (bx & 1023) << 2;     // 4 rows per block

    float gscale = gamma[0];

    if (tid < 128) {
        int kd = tid & 31, rr = tid >> 5;
        qld[kd][rr] = Q[((size_t)b * NPIX + i0 + rr) * KD + kd];
    }
    __syncthreads();                                        // B0: q ready

    // key map (m-independent): k = clamp((int)fma(e, 4096, 32768), 0, 65535)
    #define EKEY(EV, KV) { KV = (int)fmaf((EV), 4096.0f, 32768.0f); \
                           KV = KV < 0 ? 0 : (KV > 65535 ? 65535 : KV); }

    // ---- energy: 4 rows x 16 cols per thread; K float4 shared by 4 rows ----
    const float4* Kb4 = (const float4*)(Km + (size_t)b * KD * NPIX);
    unsigned lmax0 = 0u, lmax1 = 0u, lmax2 = 0u, lmax3 = 0u;
    #pragma unroll 1
    for (int g = 0; g < 4; ++g) {
        int c4 = tid + (g << 8);
        float4 a0 = {0,0,0,0}, a1 = {0,0,0,0}, a2 = {0,0,0,0}, a3 = {0,0,0,0};
        #pragma unroll 4
        for (int kd = 0; kd < KD; ++kd) {
            float4 kv = Kb4[(kd << 10) + c4];
            float4 qv = *(const float4*)qld[kd];            // broadcast b128
            a0.x = fmaf(qv.x, kv.x, a0.x); a0.y = fmaf(qv.x, kv.y, a0.y);
            a0.z = fmaf(qv.x, kv.z, a0.z); a0.w = fmaf(qv.x, kv.w, a0.w);
            a1.x = fmaf(qv.y, kv.x, a1.x); a1.y = fmaf(qv.y, kv.y, a1.y);
            a1.z = fmaf(qv.y, kv.z, a1.z); a1.w = fmaf(qv.y, kv.w, a1.w);
            a2.x = fmaf(qv.z, kv.x, a2.x); a2.y = fmaf(qv.z, kv.y, a2.y);
            a2.z = fmaf(qv.z, kv.z, a2.z); a2.w = fmaf(qv.z, kv.w, a2.w);
            a3.x = fmaf(qv.w, kv.x, a3.x); a3.y = fmaf(qv.w, kv.y, a3.y);
            a3.z = fmaf(qv.w, kv.z, a3.z); a3.w = fmaf(qv.w, kv.w, a3.w);
        }
        #define DOROW(A, R, LM) { int k0,k1,k2,k3; \
            EKEY(A.x,k0); EKEY(A.y,k1); EKEY(A.z,k2); EKEY(A.w,k3); \
            LM = max(LM, (unsigned)max(max(k0,k1),max(k2,k3))); \
            ((ushort4*)ek[R])[c4] = make_ushort4((unsigned short)k0,(unsigned short)k1, \
                                                 (unsigned short)k2,(unsigned short)k3); }
        DOROW(a0, 0, lmax0) DOROW(a1, 1, lmax1) DOROW(a2, 2, lmax2) DOROW(a3, 3, lmax3)
        #undef DOROW
    }
    #define RMAX(V, R) { unsigned v_ = (V); \
        _Pragma("unroll") \
        for (int off = 32; off; off >>= 1) \
            v_ = max(v_, (unsigned)__shfl_down((int)v_, off, 64)); \
        if (lane == 0) redk0[wv][R] = v_; }
    RMAX(lmax0, 0) RMAX(lmax1, 1) RMAX(lmax2, 2) RMAX(lmax3, 3)
    #undef RMAX
    __syncthreads();                                        // B1: keys + maxes

    // ================= per-wave from here: wave wv owns row i0+wv ==========
    const int r = wv;
    const int i = i0 + r;
    unsigned mk = max(max(redk0[0][r], redk0[1][r]), max(redk0[2][r], redk0[3][r]));
    const ushort4* ek4 = (const ushort4*)ek[r];
    unsigned* hw = h4[r];

    // wave suffix-scan over own 256-bin hist; result via own LDS slot
    #define WSCAN(RNEED, OUTB, OUTR) { \
        uint4 hh = *((const uint4*)&hw[lane << 2]); \
        unsigned s3 = hh.w, s2 = hh.w + hh.z, s1 = s2 + hh.y, s0 = s1 + hh.x; \
        unsigned X = s0; \
        _Pragma("unroll") \
        for (int off = 1; off < 64; off <<= 1) { \
            unsigned v = (unsigned)__shfl_down((int)X, off, 64); \
            if (lane + off < 64) X += v; } \
        unsigned Xn = (unsigned)__shfl_down((int)X, 1, 64); \
        if (lane == 63) Xn = 0u; \
        unsigned S0 = X, S1 = Xn + s1, S2 = Xn + s2, S3 = Xn + s3, S4 = Xn; \
        if (S0 >= (RNEED) && S1 < (RNEED)) { sh_b4[r] = (lane << 2) | 0; sh_r4[r] = (RNEED) - S1; } \
        if (S1 >= (RNEED) && S2 < (RNEED)) { sh_b4[r] = (lane << 2) | 1; sh_r4[r] = (RNEED) - S2; } \
        if (S2 >= (RNEED) && S3 < (RNEED)) { sh_b4[r] = (lane << 2) | 2; sh_r4[r] = (RNEED) - S3; } \
        if (S3 >= (RNEED) && S4 < (RNEED)) { sh_b4[r] = (lane << 2) | 3; sh_r4[r] = (RNEED) - S4; } \
        OUTB = sh_b4[r]; OUTR = sh_r4[r]; }

    // ---- pass A: hist on high byte ----
    #pragma unroll
    for (int z = 0; z < 4; ++z) hw[(z << 6) + lane] = 0u;
    #pragma unroll 4
    for (int g = 0; g < 16; ++g) {
        ushort4 kv = ek4[lane + (g << 6)];
        atomicAdd(&hw[kv.x >> 8], 1u);
        atomicAdd(&hw[kv.y >> 8], 1u);
        atomicAdd(&hw[kv.z >> 8], 1u);
        atomicAdd(&hw[kv.w >> 8], 1u);
    }
    unsigned bh, rn;
    WSCAN(KK, bh, rn)

    // ---- pass B: hist on low byte within selected high-byte bin ----
    #pragma unroll
    for (int z = 0; z < 4; ++z) hw[(z << 6) + lane] = 0u;
    #pragma unroll 4
    for (int g = 0; g < 16; ++g) {
        ushort4 kv = ek4[lane + (g << 6)];
        if ((unsigned)(kv.x >> 8) == bh) atomicAdd(&hw[kv.x & 255u], 1u);
        if ((unsigned)(kv.y >> 8) == bh) atomicAdd(&hw[kv.y & 255u], 1u);
        if ((unsigned)(kv.z >> 8) == bh) atomicAdd(&hw[kv.z & 255u], 1u);
        if ((unsigned)(kv.w >> 8) == bh) atomicAdd(&hw[kv.w & 255u], 1u);
    }
    unsigned bl, rt;
    WSCAN(rn, bl, rt)
    #undef WSCAN
    int tu = (int)((bh << 8) | bl);

    // ---- selection: register-based compaction (no atomics) ----
    unsigned base = 0u, tbase = 0u;
    float lsum = 0.f;
    #pragma unroll 4
    for (int g = 0; g < 16; ++g) {
        ushort4 kv = ek4[lane + (g << 6)];
        #pragma unroll
        for (int c = 0; c < 4; ++c) {
            int k = (c == 0) ? kv.x : (c == 1) ? kv.y : (c == 2) ? kv.z : kv.w;
            bool tie = (k == tu);
            unsigned long long tmask = __ballot(tie);
            bool sel = (k > tu);
            if (tie) {
                unsigned tix = tbase + (unsigned)__popcll(tmask & ((1ull << lane) - 1ull));
                sel = (tix < rt);
            }
            tbase += (unsigned)__popcll(tmask);
            unsigned long long smask = __ballot(sel);
            if (sel) {
                unsigned pos = base + (unsigned)__popcll(smask & ((1ull << lane) - 1ull));
                int j = ((lane + (g << 6)) << 2) | c;
                selbuf[r][pos] = ((unsigned)j << 16) | (unsigned)k;
                lsum += __expf((float)(k - (int)mk) * 0.000244140625f);
            }
            base += (unsigned)__popcll(smask);
        }
    }
    #pragma unroll
    for (int off = 32; off; off >>= 1) lsum += __shfl_xor(lsum, off, 64);
    float denom = lsum + EPSF;

    // ---- PV gather: 4 entries x 16 lanes x float4, one wave per row ----
    int eslot = lane >> 4, vq = lane & 15;
    const float4* Vb4 = (const float4*)(Vm + (size_t)b * NPIX * OD);
    const unsigned* selr = selbuf[r];
    float4 acc = make_float4(0.f, 0.f, 0.f, 0.f);
    #pragma unroll 1
    for (int s0 = 0; s0 < KK; s0 += 4) {
        int s = s0 + eslot;
        if (s < KK) {
            unsigned pk = selr[s];
            float w = __expf((float)((int)(pk & 0xFFFFu) - (int)mk) * 0.000244140625f);
            float4 v4 = Vb4[(((int)(pk >> 16)) << 4) + vq];
            acc.x = fmaf(w, v4.x, acc.x);
            acc.y = fmaf(w, v4.y, acc.y);
            acc.z = fmaf(w, v4.z, acc.z);
            acc.w = fmaf(w, v4.w, acc.w);
        }
    }
    #pragma unroll
    for (int off = 16; off <= 32; off <<= 1) {
        acc.x += __shfl_xor(acc.x, off, 64);
        acc.y += __shfl_xor(acc.y, off, 64);
        acc.z += __shfl_xor(acc.z, off, 64);
        acc.w += __shfl_xor(acc.w, off, 64);
    }
    if (lane < 16) {
        float sc = gscale / denom;
        size_t basei = ((size_t)b * CCH + (vq << 2)) * NPIX + i;
        out[basei]            = fmaf(sc, acc.x, x[basei]);
        out[basei +   NPIX]   = fmaf(sc, acc.y, x[basei +   NPIX]);
        out[basei + 2*NPIX]   = fmaf(sc, acc.z, x[basei + 2*NPIX]);
        out[basei + 3*NPIX]   = fmaf(sc, acc.w, x[basei + 3*NPIX]);
    }
}

extern "C" void kernel_launch(void* const* d_in, const int* in_sizes, int n_in,
                              void* d_out, int out_size, void* d_ws, size_t ws_size,
                              hipStream_t stream) {
    const float* x     = (const float*)d_in[0];
    const float* Wq    = (const float*)d_in[1];
    const float* bq    = (const float*)d_in[2];
    const float* Wk    = (const float*)d_in[3];
    const float* bk    = (const float*)d_in[4];
    const float* Wv    = (const float*)d_in[5];
    const float* bv    = (const float*)d_in[6];
    const float* gamma = (const float*)d_in[7];
    float* out = (float*)d_out;

    float* Q  = (float*)d_ws;
    float* Km = Q  + (size_t)BATCH * NPIX * KD;
    float* Vm = Km + (size_t)BATCH * KD * NPIX;

    qkv_kernel<<<BATCH * (NPIX / 64), 256, 0, stream>>>(x, Wq, bq, Wk, bk, Wv, bv, Q, Km, Vm);
    attn_kernel<<<BATCH * (NPIX / 4), 256, 0, stream>>>(x, Q, Km, Vm, gamma, out);
}

// Round 10
// 323.570 us; speedup vs baseline: 2.4749x; 1.1918x over previous
//
#include <hip/hip_runtime.h>

#define BATCH 4
#define CCH   64
#define NPIX  4096
#define KD    32
#define OD    64
#define KK    409       // N / TOPK
#define EPSF  1e-10f

// ---------------------------------------------------------------------------
// Kernel A: per-pixel linear projections (1x1 convs).  (unchanged)
// ---------------------------------------------------------------------------
__global__ __launch_bounds__(256) void qkv_kernel(
    const float* __restrict__ x,
    const float* __restrict__ Wq, const float* __restrict__ bq,
    const float* __restrict__ Wk, const float* __restrict__ bk,
    const float* __restrict__ Wv, const float* __restrict__ bv,
    float* __restrict__ Q, float* __restrict__ Km, float* __restrict__ Vm)
{
    __shared__ float xt[64][65];
    __shared__ float wq_s[KD * 64];
    __shared__ float wk_s[KD * 64];
    __shared__ float wv_s[OD * 64];
    __shared__ float bq_s[KD], bk_s[KD], bv_s[OD];

    int tid = threadIdx.x;
    int bx  = blockIdx.x;
    int b   = bx >> 6;
    int n0  = (bx & 63) << 6;

    for (int i = tid; i < KD * 64; i += 256) { wq_s[i] = Wq[i]; wk_s[i] = Wk[i]; }
    for (int i = tid; i < OD * 64; i += 256) wv_s[i] = Wv[i];
    if (tid < KD) { bq_s[tid] = bq[tid]; bk_s[tid] = bk[tid]; }
    if (tid < OD) bv_s[tid] = bv[tid];
    for (int i = tid; i < 64 * 64; i += 256) {
        int c = i >> 6, p = i & 63;
        xt[c][p] = x[((size_t)b * CCH + c) * NPIX + n0 + p];
    }
    __syncthreads();

    int px  = tid & 63;
    int grp = tid >> 6;
    int n   = n0 + px;

    if (grp == 0) {
        for (int o = 0; o < KD; ++o) {
            float acc = bq_s[o];
            #pragma unroll
            for (int c = 0; c < 64; ++c) acc += wq_s[o * 64 + c] * xt[c][px];
            Q[((size_t)b * NPIX + n) * KD + o] = acc;
        }
    } else if (grp == 1) {
        for (int o = 0; o < KD; ++o) {
            float acc = bk_s[o];
            #pragma unroll
            for (int c = 0; c < 64; ++c) acc += wk_s[o * 64 + c] * xt[c][px];
            Km[((size_t)b * KD + o) * NPIX + n] = acc;
        }
    } else {
        int obase = (grp - 2) * 32;
        for (int oo = 0; oo < 32; ++oo) {
            int o = obase + oo;
            float acc = bv_s[o];
            #pragma unroll
            for (int c = 0; c < 64; ++c) acc += wv_s[o * 64 + c] * xt[c][px];
            Vm[((size_t)b * NPIX + n) * OD + o] = acc;
        }
    }
}

// ---------------------------------------------------------------------------
// Kernel B: one block = 4 consecutive rows; K loads amortized 4x.
// LDS diet: selbuf (u16 indices) aliases the per-wave histogram (dead after
// WSCAN B) -> 37.5 KB total -> 4 blocks/CU.
// After one barrier, wave w owns row w end-to-end.
// ---------------------------------------------------------------------------
__global__ __launch_bounds__(256, 2) void attn_kernel(
    const float* __restrict__ x,  const float* __restrict__ Q,
    const float* __restrict__ Km, const float* __restrict__ Vm,
    const float* __restrict__ gamma, float* __restrict__ out)
{
    __shared__ __align__(16) unsigned short ek[4][NPIX];   // 32 KB keys
    __shared__ __align__(16) float qld[KD][4];             // q transposed
    __shared__ __align__(16) unsigned h4[4][256];          // per-wave hist / selbuf
    __shared__ unsigned redk0[4][4];                       // [wv][row]
    volatile __shared__ unsigned sh_b4[4], sh_r4[4];

    int tid  = threadIdx.x;
    int lane = tid & 63, wv = tid >> 6;
    int bx   = blockIdx.x;
    int b    = bx >> 10;             // 1024 blocks per batch
    int i0   = (bx & 1023) << 2;     // 4 rows per block

    float gscale = gamma[0];

    if (tid < 128) {
        int kd = tid & 31, rr = tid >> 5;
        qld[kd][rr] = Q[((size_t)b * NPIX + i0 + rr) * KD + kd];
    }
    __syncthreads();                                        // B0: q ready

    // key map (m-independent): k = clamp((int)fma(e, 4096, 32768), 0, 65535)
    #define EKEY(EV, KV) { KV = (int)fmaf((EV), 4096.0f, 32768.0f); \
                           KV = KV < 0 ? 0 : (KV > 65535 ? 65535 : KV); }

    // ---- energy: 4 rows x 16 cols per thread; K float4 shared by 4 rows ----
    const float4* Kb4 = (const float4*)(Km + (size_t)b * KD * NPIX);
    unsigned lmax0 = 0u, lmax1 = 0u, lmax2 = 0u, lmax3 = 0u;
    #pragma unroll 1
    for (int g = 0; g < 4; ++g) {
        int c4 = tid + (g << 8);
        float4 a0 = {0,0,0,0}, a1 = {0,0,0,0}, a2 = {0,0,0,0}, a3 = {0,0,0,0};
        #pragma unroll 4
        for (int kd = 0; kd < KD; ++kd) {
            float4 kv = Kb4[(kd << 10) + c4];
            float4 qv = *(const float4*)qld[kd];            // broadcast b128
            a0.x = fmaf(qv.x, kv.x, a0.x); a0.y = fmaf(qv.x, kv.y, a0.y);
            a0.z = fmaf(qv.x, kv.z, a0.z); a0.w = fmaf(qv.x, kv.w, a0.w);
            a1.x = fmaf(qv.y, kv.x, a1.x); a1.y = fmaf(qv.y, kv.y, a1.y);
            a1.z = fmaf(qv.y, kv.z, a1.z); a1.w = fmaf(qv.y, kv.w, a1.w);
            a2.x = fmaf(qv.z, kv.x, a2.x); a2.y = fmaf(qv.z, kv.y, a2.y);
            a2.z = fmaf(qv.z, kv.z, a2.z); a2.w = fmaf(qv.z, kv.w, a2.w);
            a3.x = fmaf(qv.w, kv.x, a3.x); a3.y = fmaf(qv.w, kv.y, a3.y);
            a3.z = fmaf(qv.w, kv.z, a3.z); a3.w = fmaf(qv.w, kv.w, a3.w);
        }
        #define DOROW(A, R, LM) { int k0,k1,k2,k3; \
            EKEY(A.x,k0); EKEY(A.y,k1); EKEY(A.z,k2); EKEY(A.w,k3); \
            LM = max(LM, (unsigned)max(max(k0,k1),max(k2,k3))); \
            ((ushort4*)ek[R])[c4] = make_ushort4((unsigned short)k0,(unsigned short)k1, \
                                                 (unsigned short)k2,(unsigned short)k3); }
        DOROW(a0, 0, lmax0) DOROW(a1, 1, lmax1) DOROW(a2, 2, lmax2) DOROW(a3, 3, lmax3)
        #undef DOROW
    }
    #define RMAX(V, R) { unsigned v_ = (V); \
        _Pragma("unroll") \
        for (int off = 32; off; off >>= 1) \
            v_ = max(v_, (unsigned)__shfl_down((int)v_, off, 64)); \
        if (lane == 0) redk0[wv][R] = v_; }
    RMAX(lmax0, 0) RMAX(lmax1, 1) RMAX(lmax2, 2) RMAX(lmax3, 3)
    #undef RMAX
    __syncthreads();                                        // B1: keys + maxes

    // ================= per-wave from here: wave wv owns row i0+wv ==========
    const int r = wv;
    const int i = i0 + r;
    unsigned mk = max(max(redk0[0][r], redk0[1][r]), max(redk0[2][r], redk0[3][r]));
    const ushort4* ek4 = (const ushort4*)ek[r];
    unsigned* hw = h4[r];

    // wave suffix-scan over own 256-bin hist; result via own LDS slot
    #define WSCAN(RNEED, OUTB, OUTR) { \
        uint4 hh = *((const uint4*)&hw[lane << 2]); \
        unsigned s3 = hh.w, s2 = hh.w + hh.z, s1 = s2 + hh.y, s0 = s1 + hh.x; \
        unsigned X = s0; \
        _Pragma("unroll") \
        for (int off = 1; off < 64; off <<= 1) { \
            unsigned v = (unsigned)__shfl_down((int)X, off, 64); \
            if (lane + off < 64) X += v; } \
        unsigned Xn = (unsigned)__shfl_down((int)X, 1, 64); \
        if (lane == 63) Xn = 0u; \
        unsigned S0 = X, S1 = Xn + s1, S2 = Xn + s2, S3 = Xn + s3, S4 = Xn; \
        if (S0 >= (RNEED) && S1 < (RNEED)) { sh_b4[r] = (lane << 2) | 0; sh_r4[r] = (RNEED) - S1; } \
        if (S1 >= (RNEED) && S2 < (RNEED)) { sh_b4[r] = (lane << 2) | 1; sh_r4[r] = (RNEED) - S2; } \
        if (S2 >= (RNEED) && S3 < (RNEED)) { sh_b4[r] = (lane << 2) | 2; sh_r4[r] = (RNEED) - S3; } \
        if (S3 >= (RNEED) && S4 < (RNEED)) { sh_b4[r] = (lane << 2) | 3; sh_r4[r] = (RNEED) - S4; } \
        OUTB = sh_b4[r]; OUTR = sh_r4[r]; }

    // ---- pass A: hist on high byte ----
    #pragma unroll
    for (int z = 0; z < 4; ++z) hw[(z << 6) + lane] = 0u;
    #pragma unroll 4
    for (int g = 0; g < 16; ++g) {
        ushort4 kv = ek4[lane + (g << 6)];
        atomicAdd(&hw[kv.x >> 8], 1u);
        atomicAdd(&hw[kv.y >> 8], 1u);
        atomicAdd(&hw[kv.z >> 8], 1u);
        atomicAdd(&hw[kv.w >> 8], 1u);
    }
    unsigned bh, rn;
    WSCAN(KK, bh, rn)

    // ---- pass B: hist on low byte within selected high-byte bin ----
    #pragma unroll
    for (int z = 0; z < 4; ++z) hw[(z << 6) + lane] = 0u;
    #pragma unroll 4
    for (int g = 0; g < 16; ++g) {
        ushort4 kv = ek4[lane + (g << 6)];
        if ((unsigned)(kv.x >> 8) == bh) atomicAdd(&hw[kv.x & 255u], 1u);
        if ((unsigned)(kv.y >> 8) == bh) atomicAdd(&hw[kv.y & 255u], 1u);
        if ((unsigned)(kv.z >> 8) == bh) atomicAdd(&hw[kv.z & 255u], 1u);
        if ((unsigned)(kv.w >> 8) == bh) atomicAdd(&hw[kv.w & 255u], 1u);
    }
    unsigned bl, rt;
    WSCAN(rn, bl, rt)
    #undef WSCAN
    int tu = (int)((bh << 8) | bl);

    // ---- selection: register-based compaction (no atomics) ----
    // hw is dead now -> reuse its 1KB slot as the u16 index list (409 <= 512)
    unsigned short* selr = (unsigned short*)hw;
    unsigned base = 0u, tbase = 0u;
    float lsum = 0.f;
    #pragma unroll 4
    for (int g = 0; g < 16; ++g) {
        ushort4 kv = ek4[lane + (g << 6)];
        #pragma unroll
        for (int c = 0; c < 4; ++c) {
            int k = (c == 0) ? kv.x : (c == 1) ? kv.y : (c == 2) ? kv.z : kv.w;
            bool tie = (k == tu);
            unsigned long long tmask = __ballot(tie);
            bool sel = (k > tu);
            if (tie) {
                unsigned tix = tbase + (unsigned)__popcll(tmask & ((1ull << lane) - 1ull));
                sel = (tix < rt);
            }
            tbase += (unsigned)__popcll(tmask);
            unsigned long long smask = __ballot(sel);
            if (sel) {
                unsigned pos = base + (unsigned)__popcll(smask & ((1ull << lane) - 1ull));
                int j = ((lane + (g << 6)) << 2) | c;
                selr[pos] = (unsigned short)j;
                lsum += __expf((float)(k - (int)mk) * 0.000244140625f);
            }
            base += (unsigned)__popcll(smask);
        }
    }
    #pragma unroll
    for (int off = 32; off; off >>= 1) lsum += __shfl_xor(lsum, off, 64);
    float denom = lsum + EPSF;

    // ---- PV gather: 4 entries x 16 lanes x float4, one wave per row ----
    int eslot = lane >> 4, vq = lane & 15;
    const float4* Vb4 = (const float4*)(Vm + (size_t)b * NPIX * OD);
    const unsigned short* ekr = ek[r];
    float4 acc = make_float4(0.f, 0.f, 0.f, 0.f);
    #pragma unroll 1
    for (int s0 = 0; s0 < KK; s0 += 4) {
        int s = s0 + eslot;
        if (s < KK) {
            int j = selr[s];
            int k = ekr[j];
            float w = __expf((float)(k - (int)mk) * 0.000244140625f);
            float4 v4 = Vb4[(j << 4) + vq];
            acc.x = fmaf(w, v4.x, acc.x);
            acc.y = fmaf(w, v4.y, acc.y);
            acc.z = fmaf(w, v4.z, acc.z);
            acc.w = fmaf(w, v4.w, acc.w);
        }
    }
    #pragma unroll
    for (int off = 16; off <= 32; off <<= 1) {
        acc.x += __shfl_xor(acc.x, off, 64);
        acc.y += __shfl_xor(acc.y, off, 64);
        acc.z += __shfl_xor(acc.z, off, 64);
        acc.w += __shfl_xor(acc.w, off, 64);
    }
    if (lane < 16) {
        float sc = gscale / denom;
        size_t basei = ((size_t)b * CCH + (vq << 2)) * NPIX + i;
        out[basei]            = fmaf(sc, acc.x, x[basei]);
        out[basei +   NPIX]   = fmaf(sc, acc.y, x[basei +   NPIX]);
        out[basei + 2*NPIX]   = fmaf(sc, acc.z, x[basei + 2*NPIX]);
        out[basei + 3*NPIX]   = fmaf(sc, acc.w, x[basei + 3*NPIX]);
    }
}

extern "C" void kernel_launch(void* const* d_in, const int* in_sizes, int n_in,
                              void* d_out, int out_size, void* d_ws, size_t ws_size,
                              hipStream_t stream) {
    const float* x     = (const float*)d_in[0];
    const float* Wq    = (const float*)d_in[1];
    const float* bq    = (const float*)d_in[2];
    const float* Wk    = (const float*)d_in[3];
    const float* bk    = (const float*)d_in[4];
    const float* Wv    = (const float*)d_in[5];
    const float* bv    = (const float*)d_in[6];
    const float* gamma = (const float*)d_in[7];
    float* out = (float*)d_out;

    float* Q  = (float*)d_ws;
    float* Km = Q  + (size_t)BATCH * NPIX * KD;
    float* Vm = Km + (size_t)BATCH * KD * NPIX;

    qkv_kernel<<<BATCH * (NPIX / 64), 256, 0, stream>>>(x, Wq, bq, Wk, bk, Wv, bv, Q, Km, Vm);
    attn_kernel<<<BATCH * (NPIX / 4), 256, 0, stream>>>(x, Q, Km, Vm, gamma, out);
}

// Round 13
// 317.505 us; speedup vs baseline: 2.5222x; 1.0191x over previous
//
#include <hip/hip_runtime.h>

#define BATCH 4
#define CCH   64
#define NPIX  4096
#define KD    32
#define OD    64
#define KK    409       // N / TOPK
#define EPSF  1e-10f

// ---------------------------------------------------------------------------
// Kernel A: per-pixel projections, register-blocked.
// Grid 512: blocks [0,256) compute Q+K for a 64-pixel tile; [256,512) compute V.
// Weights staged TRANSPOSED in LDS (wt[c][o], padded) so each c-step is
// 1 ds_read_b32 (x) + 4 broadcast ds_read_b128 (16 weights) + 16 FMA.
// ---------------------------------------------------------------------------
__global__ __launch_bounds__(256, 4) void qkv_kernel(
    const float* __restrict__ x,
    const float* __restrict__ Wq, const float* __restrict__ bq,
    const float* __restrict__ Wk, const float* __restrict__ bk,
    const float* __restrict__ Wv, const float* __restrict__ bv,
    float* __restrict__ Q, float* __restrict__ Km, float* __restrict__ Vm)
{
    __shared__ float xt[64][65];          // 16.25 KB (c, px)
    __shared__ float wat[64][36];         // QK: wq ; V: wv[0:32)   (pad->b128 ok)
    __shared__ float wbt[64][36];         // QK: wk ; V: wv[32:64)
    __shared__ float ba_s[32], bb_s[32];

    int tid = threadIdx.x;
    int bx  = blockIdx.x;
    bool vmode = bx >= 256;
    int tile = vmode ? bx - 256 : bx;
    int b    = tile >> 6;
    int n0   = (tile & 63) << 6;

    // stage x tile (coalesced)
    for (int i = tid; i < 64 * 64; i += 256) {
        int c = i >> 6, p = i & 63;
        xt[c][p] = x[((size_t)b * CCH + c) * NPIX + n0 + p];
    }
    // stage weights transposed
    if (!vmode) {
        for (int i = tid; i < 2048; i += 256) {
            int o = i >> 6, c = i & 63;
            wat[c][o] = Wq[i];
            wbt[c][o] = Wk[i];
        }
        if (tid < 32) { ba_s[tid] = bq[tid]; bb_s[tid] = bk[tid]; }
    } else {
        for (int i = tid; i < 4096; i += 256) {
            int o = i >> 6, c = i & 63;           // o in [0,64)
            if (o < 32) wat[c][o] = Wv[i]; else wbt[c][o - 32] = Wv[i];
        }
        if (tid < 32) { ba_s[tid] = bv[tid]; bb_s[tid] = bv[tid + 32]; }
    }
    __syncthreads();

    int px  = tid & 63;
    int grp = tid >> 6;              // 0..3
    int n   = n0 + px;
    // group -> (weight bank, o-block)
    const float (*wt)[36] = (grp < 2) ? wat : wbt;
    const float* bs = (grp < 2) ? ba_s : bb_s;
    int o0 = (grp & 1) << 4;         // 0 or 16

    float a[16];
    #pragma unroll
    for (int t = 0; t < 16; ++t) a[t] = bs[o0 + t];

    #pragma unroll 2
    for (int c = 0; c < 64; ++c) {
        float xv = xt[c][px];
        const float4* wr = (const float4*)&wt[c][o0];
        float4 w0 = wr[0], w1 = wr[1], w2 = wr[2], w3 = wr[3];
        a[0]  = fmaf(w0.x, xv, a[0]);  a[1]  = fmaf(w0.y, xv, a[1]);
        a[2]  = fmaf(w0.z, xv, a[2]);  a[3]  = fmaf(w0.w, xv, a[3]);
        a[4]  = fmaf(w1.x, xv, a[4]);  a[5]  = fmaf(w1.y, xv, a[5]);
        a[6]  = fmaf(w1.z, xv, a[6]);  a[7]  = fmaf(w1.w, xv, a[7]);
        a[8]  = fmaf(w2.x, xv, a[8]);  a[9]  = fmaf(w2.y, xv, a[9]);
        a[10] = fmaf(w2.z, xv, a[10]); a[11] = fmaf(w2.w, xv, a[11]);
        a[12] = fmaf(w3.x, xv, a[12]); a[13] = fmaf(w3.y, xv, a[13]);
        a[14] = fmaf(w3.z, xv, a[14]); a[15] = fmaf(w3.w, xv, a[15]);
    }

    if (!vmode) {
        if (grp < 2) {     // Q [b][n][kd]
            #pragma unroll
            for (int t = 0; t < 16; ++t)
                Q[((size_t)b * NPIX + n) * KD + o0 + t] = a[t];
        } else {           // K [b][kd][n]
            #pragma unroll
            for (int t = 0; t < 16; ++t)
                Km[((size_t)b * KD + o0 + t) * NPIX + n] = a[t];
        }
    } else {               // V [b][n][od], od = (grp>=2 ? 32 : 0) + o0 + t
        int ob = ((grp < 2) ? 0 : 32) + o0;
        #pragma unroll
        for (int t = 0; t < 16; ++t)
            Vm[((size_t)b * NPIX + n) * OD + ob + t] = a[t];
    }
}

// ---------------------------------------------------------------------------
// Kernel B: one block = 8 consecutive rows, 512 threads; K loads amortized 8x.
// After one barrier, wave w owns row w end-to-end (hist/scan/selection/PV).
// LDS ~73.3 KB -> 2 blocks/CU (16 waves/CU, same occupancy as 4-row version,
// half the K L2 traffic).
// ---------------------------------------------------------------------------
__global__ __launch_bounds__(512, 4) void attn_kernel(
    const float* __restrict__ x,  const float* __restrict__ Q,
    const float* __restrict__ Km, const float* __restrict__ Vm,
    const float* __restrict__ gamma, float* __restrict__ out)
{
    __shared__ __align__(16) unsigned short ek[8][NPIX];   // 64 KB keys
    __shared__ __align__(16) float qld[KD][8];             // 1 KB q transposed
    __shared__ __align__(16) unsigned h8[8][256];          // 8 KB per-wave hist
    __shared__ unsigned redk0[8][8];                       // [wv][row]
    volatile __shared__ unsigned sh_b8[8], sh_r8[8];

    int tid  = threadIdx.x;
    int lane = tid & 63, wv = tid >> 6;    // wv 0..7
    int bx   = blockIdx.x;
    int b    = bx >> 9;                    // 512 blocks per batch
    int i0   = (bx & 511) << 3;            // 8 rows per block

    float gscale = gamma[0];

    if (tid < 256) {
        int kd = tid & 31, rr = tid >> 5;  // rr 0..7
        qld[kd][rr] = Q[((size_t)b * NPIX + i0 + rr) * KD + kd];
    }
    __syncthreads();                                        // B0: q ready

    // key map (m-independent): k = clamp((int)fma(e, 4096, 32768), 0, 65535)
    #define EKEY(EV, KV) { KV = (int)fmaf((EV), 4096.0f, 32768.0f); \
                           KV = KV < 0 ? 0 : (KV > 65535 ? 65535 : KV); }

    // ---- energy: 8 rows x 8 cols per thread; K float4 shared by 8 rows ----
    const float4* Kb4 = (const float4*)(Km + (size_t)b * KD * NPIX);
    unsigned lm0 = 0u, lm1 = 0u, lm2 = 0u, lm3 = 0u,
             lm4 = 0u, lm5 = 0u, lm6 = 0u, lm7 = 0u;
    #pragma unroll 1
    for (int g = 0; g < 2; ++g) {
        int c4 = tid + (g << 9);           // float4 column index 0..1023
        float4 a0 = {0,0,0,0}, a1 = {0,0,0,0}, a2 = {0,0,0,0}, a3 = {0,0,0,0};
        float4 a4 = {0,0,0,0}, a5 = {0,0,0,0}, a6 = {0,0,0,0}, a7 = {0,0,0,0};
        #pragma unroll 4
        for (int kd = 0; kd < KD; ++kd) {
            float4 kv = Kb4[(kd << 10) + c4];
            float4 qA = *(const float4*)&qld[kd][0];        // rows 0-3 (broadcast)
            float4 qB = *(const float4*)&qld[kd][4];        // rows 4-7
            #define FMA4(A, S) { A.x = fmaf((S), kv.x, A.x); A.y = fmaf((S), kv.y, A.y); \
                                 A.z = fmaf((S), kv.z, A.z); A.w = fmaf((S), kv.w, A.w); }
            FMA4(a0, qA.x) FMA4(a1, qA.y) FMA4(a2, qA.z) FMA4(a3, qA.w)
            FMA4(a4, qB.x) FMA4(a5, qB.y) FMA4(a6, qB.z) FMA4(a7, qB.w)
            #undef FMA4
        }
        #define DOROW(A, R, LM) { int k0,k1,k2,k3; \
            EKEY(A.x,k0); EKEY(A.y,k1); EKEY(A.z,k2); EKEY(A.w,k3); \
            LM = max(LM, (unsigned)max(max(k0,k1),max(k2,k3))); \
            ((ushort4*)ek[R])[c4] = make_ushort4((unsigned short)k0,(unsigned short)k1, \
                                                 (unsigned short)k2,(unsigned short)k3); }
        DOROW(a0,0,lm0) DOROW(a1,1,lm1) DOROW(a2,2,lm2) DOROW(a3,3,lm3)
        DOROW(a4,4,lm4) DOROW(a5,5,lm5) DOROW(a6,6,lm6) DOROW(a7,7,lm7)
        #undef DOROW
    }
    #define RMAX(V, R) { unsigned v_ = (V); \
        _Pragma("unroll") \
        for (int off = 32; off; off >>= 1) \
            v_ = max(v_, (unsigned)__shfl_down((int)v_, off, 64)); \
        if (lane == 0) redk0[wv][R] = v_; }
    RMAX(lm0,0) RMAX(lm1,1) RMAX(lm2,2) RMAX(lm3,3)
    RMAX(lm4,4) RMAX(lm5,5) RMAX(lm6,6) RMAX(lm7,7)
    #undef RMAX
    __syncthreads();                                        // B1: keys + maxes

    // ================= per-wave from here: wave wv owns row i0+wv ==========
    const int r = wv;
    const int i = i0 + r;
    unsigned mk = 0u;
    #pragma unroll
    for (int w = 0; w < 8; ++w) mk = max(mk, redk0[w][r]);
    const ushort4* ek4 = (const ushort4*)ek[r];
    unsigned* hw = h8[r];

    #define WSCAN(RNEED, OUTB, OUTR) { \
        uint4 hh = *((const uint4*)&hw[lane << 2]); \
        unsigned s3 = hh.w, s2 = hh.w + hh.z, s1 = s2 + hh.y, s0 = s1 + hh.x; \
        unsigned X = s0; \
        _Pragma("unroll") \
        for (int off = 1; off < 64; off <<= 1) { \
            unsigned v = (unsigned)__shfl_down((int)X, off, 64); \
            if (lane + off < 64) X += v; } \
        unsigned Xn = (unsigned)__shfl_down((int)X, 1, 64); \
        if (lane == 63) Xn = 0u; \
        unsigned S0 = X, S1 = Xn + s1, S2 = Xn + s2, S3 = Xn + s3, S4 = Xn; \
        if (S0 >= (RNEED) && S1 < (RNEED)) { sh_b8[r] = (lane << 2) | 0; sh_r8[r] = (RNEED) - S1; } \
        if (S1 >= (RNEED) && S2 < (RNEED)) { sh_b8[r] = (lane << 2) | 1; sh_r8[r] = (RNEED) - S2; } \
        if (S2 >= (RNEED) && S3 < (RNEED)) { sh_b8[r] = (lane << 2) | 2; sh_r8[r] = (RNEED) - S3; } \
        if (S3 >= (RNEED) && S4 < (RNEED)) { sh_b8[r] = (lane << 2) | 3; sh_r8[r] = (RNEED) - S4; } \
        OUTB = sh_b8[r]; OUTR = sh_r8[r]; }

    // ---- pass A: hist on high byte ----
    #pragma unroll
    for (int z = 0; z < 4; ++z) hw[(z << 6) + lane] = 0u;
    #pragma unroll 4
    for (int g = 0; g < 16; ++g) {
        ushort4 kv = ek4[lane + (g << 6)];
        atomicAdd(&hw[kv.x >> 8], 1u);
        atomicAdd(&hw[kv.y >> 8], 1u);
        atomicAdd(&hw[kv.z >> 8], 1u);
        atomicAdd(&hw[kv.w >> 8], 1u);
    }
    unsigned bh, rn;
    WSCAN(KK, bh, rn)

    // ---- pass B: hist on low byte within selected high-byte bin ----
    #pragma unroll
    for (int z = 0; z < 4; ++z) hw[(z << 6) + lane] = 0u;
    #pragma unroll 4
    for (int g = 0; g < 16; ++g) {
        ushort4 kv = ek4[lane + (g << 6)];
        if ((unsigned)(kv.x >> 8) == bh) atomicAdd(&hw[kv.x & 255u], 1u);
        if ((unsigned)(kv.y >> 8) == bh) atomicAdd(&hw[kv.y & 255u], 1u);
        if ((unsigned)(kv.z >> 8) == bh) atomicAdd(&hw[kv.z & 255u], 1u);
        if ((unsigned)(kv.w >> 8) == bh) atomicAdd(&hw[kv.w & 255u], 1u);
    }
    unsigned bl, rt;
    WSCAN(rn, bl, rt)
    #undef WSCAN
    int tu = (int)((bh << 8) | bl);

    // ---- selection: register-based compaction (no atomics) ----
    // hw dead -> reuse its 1KB slot as the u16 index list (409*2 = 818 B)
    unsigned short* selr = (unsigned short*)hw;
    unsigned base = 0u, tbase = 0u;
    float lsum = 0.f;
    #pragma unroll 4
    for (int g = 0; g < 16; ++g) {
        ushort4 kv = ek4[lane + (g << 6)];
        #pragma unroll
        for (int c = 0; c < 4; ++c) {
            int k = (c == 0) ? kv.x : (c == 1) ? kv.y : (c == 2) ? kv.z : kv.w;
            bool tie = (k == tu);
            unsigned long long tmask = __ballot(tie);
            bool sel = (k > tu);
            if (tie) {
                unsigned tix = tbase + (unsigned)__popcll(tmask & ((1ull << lane) - 1ull));
                sel = (tix < rt);
            }
            tbase += (unsigned)__popcll(tmask);
            unsigned long long smask = __ballot(sel);
            if (sel) {
                unsigned pos = base + (unsigned)__popcll(smask & ((1ull << lane) - 1ull));
                int j = ((lane + (g << 6)) << 2) | c;
                selr[pos] = (unsigned short)j;
                lsum += __expf((float)(k - (int)mk) * 0.000244140625f);
            }
            base += (unsigned)__popcll(smask);
        }
    }
    #pragma unroll
    for (int off = 32; off; off >>= 1) lsum += __shfl_xor(lsum, off, 64);
    float denom = lsum + EPSF;

    // ---- PV gather: 4 entries x 16 lanes x float4, one wave per row ----
    int eslot = lane >> 4, vq = lane & 15;
    const float4* Vb4 = (const float4*)(Vm + (size_t)b * NPIX * OD);
    const unsigned short* ekr = ek[r];
    float4 acc = make_float4(0.f, 0.f, 0.f, 0.f);
    #pragma unroll 2
    for (int s0 = 0; s0 < KK; s0 += 4) {
        int s = s0 + eslot;
        if (s < KK) {
            int j = selr[s];
            int k = ekr[j];
            float w = __expf((float)(k - (int)mk) * 0.000244140625f);
            float4 v4 = Vb4[(j << 4) + vq];
            acc.x = fmaf(w, v4.x, acc.x);
            acc.y = fmaf(w, v4.y, acc.y);
            acc.z = fmaf(w, v4.z, acc.z);
            acc.w = fmaf(w, v4.w, acc.w);
        }
    }
    #pragma unroll
    for (int off = 16; off <= 32; off <<= 1) {
        acc.x += __shfl_xor(acc.x, off, 64);
        acc.y += __shfl_xor(acc.y, off, 64);
        acc.z += __shfl_xor(acc.z, off, 64);
        acc.w += __shfl_xor(acc.w, off, 64);
    }
    if (lane < 16) {
        float sc = gscale / denom;
        size_t basei = ((size_t)b * CCH + (vq << 2)) * NPIX + i;
        out[basei]            = fmaf(sc, acc.x, x[basei]);
        out[basei +   NPIX]   = fmaf(sc, acc.y, x[basei +   NPIX]);
        out[basei + 2*NPIX]   = fmaf(sc, acc.z, x[basei + 2*NPIX]);
        out[basei + 3*NPIX]   = fmaf(sc, acc.w, x[basei + 3*NPIX]);
    }
}

extern "C" void kernel_launch(void* const* d_in, const int* in_sizes, int n_in,
                              void* d_out, int out_size, void* d_ws, size_t ws_size,
                              hipStream_t stream) {
    const float* x     = (const float*)d_in[0];
    const float* Wq    = (const float*)d_in[1];
    const float* bq    = (const float*)d_in[2];
    const float* Wk    = (const float*)d_in[3];
    const float* bk    = (const float*)d_in[4];
    const float* Wv    = (const float*)d_in[5];
    const float* bv    = (const float*)d_in[6];
    const float* gamma = (const float*)d_in[7];
    float* out = (float*)d_out;

    float* Q  = (float*)d_ws;
    float* Km = Q  + (size_t)BATCH * NPIX * KD;
    float* Vm = Km + (size_t)BATCH * KD * NPIX;

    qkv_kernel<<<512, 256, 0, stream>>>(x, Wq, bq, Wk, bk, Wv, bv, Q, Km, Vm);
    attn_kernel<<<BATCH * (NPIX / 8), 512, 0, stream>>>(x, Q, Km, Vm, gamma, out);
}

// Round 14
// 311.185 us; speedup vs baseline: 2.5734x; 1.0203x over previous
//
#include <hip/hip_runtime.h>

#define BATCH 4
#define CCH   64
#define NPIX  4096
#define KD    32
#define OD    64
#define KK    409       // N / TOPK
#define EPSF  1e-10f
#define HSLOT 412       // u32 per wave slot: 256 hist bins OR 409 packed (j|w)

// ---------------------------------------------------------------------------
// Kernel A: per-pixel projections, register-blocked.  (unchanged from R13)
// ---------------------------------------------------------------------------
__global__ __launch_bounds__(256, 4) void qkv_kernel(
    const float* __restrict__ x,
    const float* __restrict__ Wq, const float* __restrict__ bq,
    const float* __restrict__ Wk, const float* __restrict__ bk,
    const float* __restrict__ Wv, const float* __restrict__ bv,
    float* __restrict__ Q, float* __restrict__ Km, float* __restrict__ Vm)
{
    __shared__ float xt[64][65];
    __shared__ float wat[64][36];
    __shared__ float wbt[64][36];
    __shared__ float ba_s[32], bb_s[32];

    int tid = threadIdx.x;
    int bx  = blockIdx.x;
    bool vmode = bx >= 256;
    int tile = vmode ? bx - 256 : bx;
    int b    = tile >> 6;
    int n0   = (tile & 63) << 6;

    for (int i = tid; i < 64 * 64; i += 256) {
        int c = i >> 6, p = i & 63;
        xt[c][p] = x[((size_t)b * CCH + c) * NPIX + n0 + p];
    }
    if (!vmode) {
        for (int i = tid; i < 2048; i += 256) {
            int o = i >> 6, c = i & 63;
            wat[c][o] = Wq[i];
            wbt[c][o] = Wk[i];
        }
        if (tid < 32) { ba_s[tid] = bq[tid]; bb_s[tid] = bk[tid]; }
    } else {
        for (int i = tid; i < 4096; i += 256) {
            int o = i >> 6, c = i & 63;
            if (o < 32) wat[c][o] = Wv[i]; else wbt[c][o - 32] = Wv[i];
        }
        if (tid < 32) { ba_s[tid] = bv[tid]; bb_s[tid] = bv[tid + 32]; }
    }
    __syncthreads();

    int px  = tid & 63;
    int grp = tid >> 6;
    int n   = n0 + px;
    const float (*wt)[36] = (grp < 2) ? wat : wbt;
    const float* bs = (grp < 2) ? ba_s : bb_s;
    int o0 = (grp & 1) << 4;

    float a[16];
    #pragma unroll
    for (int t = 0; t < 16; ++t) a[t] = bs[o0 + t];

    #pragma unroll 2
    for (int c = 0; c < 64; ++c) {
        float xv = xt[c][px];
        const float4* wr = (const float4*)&wt[c][o0];
        float4 w0 = wr[0], w1 = wr[1], w2 = wr[2], w3 = wr[3];
        a[0]  = fmaf(w0.x, xv, a[0]);  a[1]  = fmaf(w0.y, xv, a[1]);
        a[2]  = fmaf(w0.z, xv, a[2]);  a[3]  = fmaf(w0.w, xv, a[3]);
        a[4]  = fmaf(w1.x, xv, a[4]);  a[5]  = fmaf(w1.y, xv, a[5]);
        a[6]  = fmaf(w1.z, xv, a[6]);  a[7]  = fmaf(w1.w, xv, a[7]);
        a[8]  = fmaf(w2.x, xv, a[8]);  a[9]  = fmaf(w2.y, xv, a[9]);
        a[10] = fmaf(w2.z, xv, a[10]); a[11] = fmaf(w2.w, xv, a[11]);
        a[12] = fmaf(w3.x, xv, a[12]); a[13] = fmaf(w3.y, xv, a[13]);
        a[14] = fmaf(w3.z, xv, a[14]); a[15] = fmaf(w3.w, xv, a[15]);
    }

    if (!vmode) {
        if (grp < 2) {
            #pragma unroll
            for (int t = 0; t < 16; ++t)
                Q[((size_t)b * NPIX + n) * KD + o0 + t] = a[t];
        } else {
            #pragma unroll
            for (int t = 0; t < 16; ++t)
                Km[((size_t)b * KD + o0 + t) * NPIX + n] = a[t];
        }
    } else {
        int ob = ((grp < 2) ? 0 : 32) + o0;
        #pragma unroll
        for (int t = 0; t < 16; ++t)
            Vm[((size_t)b * NPIX + n) * OD + ob + t] = a[t];
    }
}

// ---------------------------------------------------------------------------
// Kernel B: 8 rows/block, 512 threads.
//   - pass-A histogram fused into the energy phase (keys in registers)
//   - selection packs (j<<16)|bf16(w) -> PV is 1 LDS read + 2-op unpack,
//     no second LDS hop, no redundant exp
// ---------------------------------------------------------------------------
__global__ __launch_bounds__(512, 4) void attn_kernel(
    const float* __restrict__ x,  const float* __restrict__ Q,
    const float* __restrict__ Km, const float* __restrict__ Vm,
    const float* __restrict__ gamma, float* __restrict__ out)
{
    __shared__ __align__(16) unsigned short ek[8][NPIX];   // 64 KB keys
    __shared__ __align__(16) float qld[KD][8];             // 1 KB q transposed
    __shared__ __align__(16) unsigned h8[8][HSLOT];        // 12.9 KB hist/selbuf
    __shared__ unsigned redk0[8][8];
    volatile __shared__ unsigned sh_b8[8], sh_r8[8];

    int tid  = threadIdx.x;
    int lane = tid & 63, wv = tid >> 6;
    int bx   = blockIdx.x;
    int b    = bx >> 9;
    int i0   = (bx & 511) << 3;

    float gscale = gamma[0];

    // zero all histograms BEFORE energy (hist A is built during energy)
    for (int z = tid; z < 8 * HSLOT; z += 512) (&h8[0][0])[z] = 0u;
    if (tid < 256) {
        int kd = tid & 31, rr = tid >> 5;
        qld[kd][rr] = Q[((size_t)b * NPIX + i0 + rr) * KD + kd];
    }
    __syncthreads();                                        // B0

    #define EKEY(EV, KV) { KV = (int)fmaf((EV), 4096.0f, 32768.0f); \
                           KV = KV < 0 ? 0 : (KV > 65535 ? 65535 : KV); }

    // ---- energy: 8 rows x 8 cols/thread; keys + inline pass-A hist ----
    const float4* Kb4 = (const float4*)(Km + (size_t)b * KD * NPIX);
    unsigned lm0 = 0u, lm1 = 0u, lm2 = 0u, lm3 = 0u,
             lm4 = 0u, lm5 = 0u, lm6 = 0u, lm7 = 0u;
    #pragma unroll 1
    for (int g = 0; g < 2; ++g) {
        int c4 = tid + (g << 9);
        float4 a0 = {0,0,0,0}, a1 = {0,0,0,0}, a2 = {0,0,0,0}, a3 = {0,0,0,0};
        float4 a4 = {0,0,0,0}, a5 = {0,0,0,0}, a6 = {0,0,0,0}, a7 = {0,0,0,0};
        #pragma unroll 4
        for (int kd = 0; kd < KD; ++kd) {
            float4 kv = Kb4[(kd << 10) + c4];
            float4 qA = *(const float4*)&qld[kd][0];
            float4 qB = *(const float4*)&qld[kd][4];
            #define FMA4(A, S) { A.x = fmaf((S), kv.x, A.x); A.y = fmaf((S), kv.y, A.y); \
                                 A.z = fmaf((S), kv.z, A.z); A.w = fmaf((S), kv.w, A.w); }
            FMA4(a0, qA.x) FMA4(a1, qA.y) FMA4(a2, qA.z) FMA4(a3, qA.w)
            FMA4(a4, qB.x) FMA4(a5, qB.y) FMA4(a6, qB.z) FMA4(a7, qB.w)
            #undef FMA4
        }
        #define DOROW(A, R, LM) { int k0,k1,k2,k3; \
            EKEY(A.x,k0); EKEY(A.y,k1); EKEY(A.z,k2); EKEY(A.w,k3); \
            LM = max(LM, (unsigned)max(max(k0,k1),max(k2,k3))); \
            ((ushort4*)ek[R])[c4] = make_ushort4((unsigned short)k0,(unsigned short)k1, \
                                                 (unsigned short)k2,(unsigned short)k3); \
            atomicAdd(&h8[R][k0 >> 8], 1u); \
            atomicAdd(&h8[R][k1 >> 8], 1u); \
            atomicAdd(&h8[R][k2 >> 8], 1u); \
            atomicAdd(&h8[R][k3 >> 8], 1u); }
        DOROW(a0,0,lm0) DOROW(a1,1,lm1) DOROW(a2,2,lm2) DOROW(a3,3,lm3)
        DOROW(a4,4,lm4) DOROW(a5,5,lm5) DOROW(a6,6,lm6) DOROW(a7,7,lm7)
        #undef DOROW
    }
    #define RMAX(V, R) { unsigned v_ = (V); \
        _Pragma("unroll") \
        for (int off = 32; off; off >>= 1) \
            v_ = max(v_, (unsigned)__shfl_down((int)v_, off, 64)); \
        if (lane == 0) redk0[wv][R] = v_; }
    RMAX(lm0,0) RMAX(lm1,1) RMAX(lm2,2) RMAX(lm3,3)
    RMAX(lm4,4) RMAX(lm5,5) RMAX(lm6,6) RMAX(lm7,7)
    #undef RMAX
    __syncthreads();                                        // B1: keys+hist+maxes

    // ================= per-wave: wave wv owns row i0+wv =====================
    const int r = wv;
    const int i = i0 + r;
    unsigned mk = 0u;
    #pragma unroll
    for (int w = 0; w < 8; ++w) mk = max(mk, redk0[w][r]);
    const ushort4* ek4 = (const ushort4*)ek[r];
    unsigned* hw = h8[r];

    #define WSCAN(RNEED, OUTB, OUTR) { \
        uint4 hh = *((const uint4*)&hw[lane << 2]); \
        unsigned s3 = hh.w, s2 = hh.w + hh.z, s1 = s2 + hh.y, s0 = s1 + hh.x; \
        unsigned X = s0; \
        _Pragma("unroll") \
        for (int off = 1; off < 64; off <<= 1) { \
            unsigned v = (unsigned)__shfl_down((int)X, off, 64); \
            if (lane + off < 64) X += v; } \
        unsigned Xn = (unsigned)__shfl_down((int)X, 1, 64); \
        if (lane == 63) Xn = 0u; \
        unsigned S0 = X, S1 = Xn + s1, S2 = Xn + s2, S3 = Xn + s3, S4 = Xn; \
        if (S0 >= (RNEED) && S1 < (RNEED)) { sh_b8[r] = (lane << 2) | 0; sh_r8[r] = (RNEED) - S1; } \
        if (S1 >= (RNEED) && S2 < (RNEED)) { sh_b8[r] = (lane << 2) | 1; sh_r8[r] = (RNEED) - S2; } \
        if (S2 >= (RNEED) && S3 < (RNEED)) { sh_b8[r] = (lane << 2) | 2; sh_r8[r] = (RNEED) - S3; } \
        if (S3 >= (RNEED) && S4 < (RNEED)) { sh_b8[r] = (lane << 2) | 3; sh_r8[r] = (RNEED) - S4; } \
        OUTB = sh_b8[r]; OUTR = sh_r8[r]; }

    // ---- pass A result: hist already built during energy ----
    unsigned bh, rn;
    WSCAN(KK, bh, rn)

    // ---- pass B: hist on low byte within selected high-byte bin ----
    #pragma unroll
    for (int z = 0; z < 4; ++z) hw[(z << 6) + lane] = 0u;
    #pragma unroll 4
    for (int g = 0; g < 16; ++g) {
        ushort4 kv = ek4[lane + (g << 6)];
        if ((unsigned)(kv.x >> 8) == bh) atomicAdd(&hw[kv.x & 255u], 1u);
        if ((unsigned)(kv.y >> 8) == bh) atomicAdd(&hw[kv.y & 255u], 1u);
        if ((unsigned)(kv.z >> 8) == bh) atomicAdd(&hw[kv.z & 255u], 1u);
        if ((unsigned)(kv.w >> 8) == bh) atomicAdd(&hw[kv.w & 255u], 1u);
    }
    unsigned bl, rt;
    WSCAN(rn, bl, rt)
    #undef WSCAN
    int tu = (int)((bh << 8) | bl);

    // ---- selection: register compaction; pack (j<<16)|bf16(w) ----
    unsigned* selw32 = hw;           // hist B dead; 409 u32 <= HSLOT
    unsigned base = 0u, tbase = 0u;
    float lsum = 0.f;
    #pragma unroll 4
    for (int g = 0; g < 16; ++g) {
        ushort4 kv = ek4[lane + (g << 6)];
        #pragma unroll
        for (int c = 0; c < 4; ++c) {
            int k = (c == 0) ? kv.x : (c == 1) ? kv.y : (c == 2) ? kv.z : kv.w;
            bool tie = (k == tu);
            unsigned long long tmask = __ballot(tie);
            bool sel = (k > tu);
            if (tie) {
                unsigned tix = tbase + (unsigned)__popcll(tmask & ((1ull << lane) - 1ull));
                sel = (tix < rt);
            }
            tbase += (unsigned)__popcll(tmask);
            unsigned long long smask = __ballot(sel);
            if (sel) {
                unsigned pos = base + (unsigned)__popcll(smask & ((1ull << lane) - 1ull));
                int j = ((lane + (g << 6)) << 2) | c;
                float w = __expf((float)(k - (int)mk) * 0.000244140625f);
                lsum += w;
                selw32[pos] = ((unsigned)j << 16) |
                              ((__float_as_uint(w) + 0x8000u) >> 16);
            }
            base += (unsigned)__popcll(smask);
        }
    }
    #pragma unroll
    for (int off = 32; off; off >>= 1) lsum += __shfl_xor(lsum, off, 64);
    float denom = lsum + EPSF;

    // ---- PV gather: 4 entries x 16 lanes x float4, one wave per row ----
    int eslot = lane >> 4, vq = lane & 15;
    const float4* Vb4 = (const float4*)(Vm + (size_t)b * NPIX * OD);
    float4 acc = make_float4(0.f, 0.f, 0.f, 0.f);
    #pragma unroll 2
    for (int s0 = 0; s0 < KK; s0 += 4) {
        int s = s0 + eslot;
        if (s < KK) {
            unsigned pk = selw32[s];
            float w = __uint_as_float(pk << 16);   // bf16 -> f32
            int j   = (int)(pk >> 16);
            float4 v4 = Vb4[(j << 4) + vq];
            acc.x = fmaf(w, v4.x, acc.x);
            acc.y = fmaf(w, v4.y, acc.y);
            acc.z = fmaf(w, v4.z, acc.z);
            acc.w = fmaf(w, v4.w, acc.w);
        }
    }
    #pragma unroll
    for (int off = 16; off <= 32; off <<= 1) {
        acc.x += __shfl_xor(acc.x, off, 64);
        acc.y += __shfl_xor(acc.y, off, 64);
        acc.z += __shfl_xor(acc.z, off, 64);
        acc.w += __shfl_xor(acc.w, off, 64);
    }
    if (lane < 16) {
        float sc = gscale / denom;
        size_t basei = ((size_t)b * CCH + (vq << 2)) * NPIX + i;
        out[basei]            = fmaf(sc, acc.x, x[basei]);
        out[basei +   NPIX]   = fmaf(sc, acc.y, x[basei +   NPIX]);
        out[basei + 2*NPIX]   = fmaf(sc, acc.z, x[basei + 2*NPIX]);
        out[basei + 3*NPIX]   = fmaf(sc, acc.w, x[basei + 3*NPIX]);
    }
}

extern "C" void kernel_launch(void* const* d_in, const int* in_sizes, int n_in,
                              void* d_out, int out_size, void* d_ws, size_t ws_size,
                              hipStream_t stream) {
    const float* x     = (const float*)d_in[0];
    const float* Wq    = (const float*)d_in[1];
    const float* bq    = (const float*)d_in[2];
    const float* Wk    = (const float*)d_in[3];
    const float* bk    = (const float*)d_in[4];
    const float* Wv    = (const float*)d_in[5];
    const float* bv    = (const float*)d_in[6];
    const float* gamma = (const float*)d_in[7];
    float* out = (float*)d_out;

    float* Q  = (float*)d_ws;
    float* Km = Q  + (size_t)BATCH * NPIX * KD;
    float* Vm = Km + (size_t)BATCH * KD * NPIX;

    qkv_kernel<<<512, 256, 0, stream>>>(x, Wq, bq, Wk, bk, Wv, bv, Q, Km, Vm);
    attn_kernel<<<BATCH * (NPIX / 8), 512, 0, stream>>>(x, Q, Km, Vm, gamma, out);
}

// Round 15
// 277.375 us; speedup vs baseline: 2.8871x; 1.1219x over previous
//
#include <hip/hip_runtime.h>

#define BATCH 4
#define CCH   64
#define NPIX  4096
#define KD    32
#define OD    64
#define KK    409       // N / TOPK
#define EPSF  1e-10f
#define HSLOT 412       // u32 per wave slot: 256 hist bins OR 409 packed (j|w)

// ---------------------------------------------------------------------------
// Kernel A: per-pixel projections, register-blocked.  (unchanged)
// ---------------------------------------------------------------------------
__global__ __launch_bounds__(256, 4) void qkv_kernel(
    const float* __restrict__ x,
    const float* __restrict__ Wq, const float* __restrict__ bq,
    const float* __restrict__ Wk, const float* __restrict__ bk,
    const float* __restrict__ Wv, const float* __restrict__ bv,
    float* __restrict__ Q, float* __restrict__ Km, float* __restrict__ Vm)
{
    __shared__ float xt[64][65];
    __shared__ float wat[64][36];
    __shared__ float wbt[64][36];
    __shared__ float ba_s[32], bb_s[32];

    int tid = threadIdx.x;
    int bx  = blockIdx.x;
    bool vmode = bx >= 256;
    int tile = vmode ? bx - 256 : bx;
    int b    = tile >> 6;
    int n0   = (tile & 63) << 6;

    for (int i = tid; i < 64 * 64; i += 256) {
        int c = i >> 6, p = i & 63;
        xt[c][p] = x[((size_t)b * CCH + c) * NPIX + n0 + p];
    }
    if (!vmode) {
        for (int i = tid; i < 2048; i += 256) {
            int o = i >> 6, c = i & 63;
            wat[c][o] = Wq[i];
            wbt[c][o] = Wk[i];
        }
        if (tid < 32) { ba_s[tid] = bq[tid]; bb_s[tid] = bk[tid]; }
    } else {
        for (int i = tid; i < 4096; i += 256) {
            int o = i >> 6, c = i & 63;
            if (o < 32) wat[c][o] = Wv[i]; else wbt[c][o - 32] = Wv[i];
        }
        if (tid < 32) { ba_s[tid] = bv[tid]; bb_s[tid] = bv[tid + 32]; }
    }
    __syncthreads();

    int px  = tid & 63;
    int grp = tid >> 6;
    int n   = n0 + px;
    const float (*wt)[36] = (grp < 2) ? wat : wbt;
    const float* bs = (grp < 2) ? ba_s : bb_s;
    int o0 = (grp & 1) << 4;

    float a[16];
    #pragma unroll
    for (int t = 0; t < 16; ++t) a[t] = bs[o0 + t];

    #pragma unroll 2
    for (int c = 0; c < 64; ++c) {
        float xv = xt[c][px];
        const float4* wr = (const float4*)&wt[c][o0];
        float4 w0 = wr[0], w1 = wr[1], w2 = wr[2], w3 = wr[3];
        a[0]  = fmaf(w0.x, xv, a[0]);  a[1]  = fmaf(w0.y, xv, a[1]);
        a[2]  = fmaf(w0.z, xv, a[2]);  a[3]  = fmaf(w0.w, xv, a[3]);
        a[4]  = fmaf(w1.x, xv, a[4]);  a[5]  = fmaf(w1.y, xv, a[5]);
        a[6]  = fmaf(w1.z, xv, a[6]);  a[7]  = fmaf(w1.w, xv, a[7]);
        a[8]  = fmaf(w2.x, xv, a[8]);  a[9]  = fmaf(w2.y, xv, a[9]);
        a[10] = fmaf(w2.z, xv, a[10]); a[11] = fmaf(w2.w, xv, a[11]);
        a[12] = fmaf(w3.x, xv, a[12]); a[13] = fmaf(w3.y, xv, a[13]);
        a[14] = fmaf(w3.z, xv, a[14]); a[15] = fmaf(w3.w, xv, a[15]);
    }

    if (!vmode) {
        if (grp < 2) {
            #pragma unroll
            for (int t = 0; t < 16; ++t)
                Q[((size_t)b * NPIX + n) * KD + o0 + t] = a[t];
        } else {
            #pragma unroll
            for (int t = 0; t < 16; ++t)
                Km[((size_t)b * KD + o0 + t) * NPIX + n] = a[t];
        }
    } else {
        int ob = ((grp < 2) ? 0 : 32) + o0;
        #pragma unroll
        for (int t = 0; t < 16; ++t)
            Vm[((size_t)b * NPIX + n) * OD + ob + t] = a[t];
    }
}

// ---------------------------------------------------------------------------
// Kernel B: 8 rows/block, 512 threads.
//   - q in SGPRs via uniform scalar loads (4 chunks of 64) -> ZERO DS ops in
//     the energy loop (was 128 ds_read_b128/thread)
//   - single kd pass covering both column groups (16 float4 accumulators;
//     VGPR is free up to 128 since we're LDS-capped at 2 blocks/CU)
//   - pass-A hist fused into energy; (j<<16)|bf16(w) packed selection; PV x4
// ---------------------------------------------------------------------------
__global__ __launch_bounds__(512, 4) void attn_kernel(
    const float* __restrict__ x,  const float* __restrict__ Q,
    const float* __restrict__ Km, const float* __restrict__ Vm,
    const float* __restrict__ gamma, float* __restrict__ out)
{
    __shared__ __align__(16) unsigned short ek[8][NPIX];   // 64 KB keys
    __shared__ __align__(16) unsigned h8[8][HSLOT];        // 12.9 KB hist/selbuf
    __shared__ unsigned redk0[8][8];
    volatile __shared__ unsigned sh_b8[8], sh_r8[8];

    int tid  = threadIdx.x;
    int lane = tid & 63, wv = tid >> 6;
    int bx   = blockIdx.x;
    int b    = bx >> 9;
    int i0   = (bx & 511) << 3;

    float gscale = gamma[0];

    // zero all histograms BEFORE energy (pass-A hist is built during energy)
    for (int z = tid; z < 8 * HSLOT; z += 512) (&h8[0][0])[z] = 0u;
    __syncthreads();                                        // B0

    #define EKEY(EV, KV) { KV = (int)fmaf((EV), 4096.0f, 32768.0f); \
                           KV = KV < 0 ? 0 : (KV > 65535 ? 65535 : KV); }

    // ---- energy: 8 rows x 16 cols/thread, q from SGPRs (uniform loads) ----
    const float*  Qb  = Q + ((size_t)b * NPIX + i0) * KD;   // 8x32 contiguous
    const float4* Kb4 = (const float4*)(Km + (size_t)b * KD * NPIX);
    int c4a = tid, c4b = tid + 512;

    float4 a0 = {0,0,0,0}, a1 = {0,0,0,0}, a2 = {0,0,0,0}, a3 = {0,0,0,0};
    float4 a4 = {0,0,0,0}, a5 = {0,0,0,0}, a6 = {0,0,0,0}, a7 = {0,0,0,0};
    float4 b0 = {0,0,0,0}, b1 = {0,0,0,0}, b2 = {0,0,0,0}, b3 = {0,0,0,0};
    float4 b4 = {0,0,0,0}, b5 = {0,0,0,0}, b6 = {0,0,0,0}, b7 = {0,0,0,0};

    #pragma unroll 1
    for (int kc = 0; kc < 4; ++kc) {                        // kd chunks of 8
        #pragma unroll 2
        for (int dk = 0; dk < 8; ++dk) {
            int kd = (kc << 3) + dk;
            float4 kva = Kb4[(kd << 10) + c4a];
            float4 kvb = Kb4[(kd << 10) + c4b];
            // block-uniform q values -> scalar loads / SGPR operands
            float q0 = Qb[0*KD + kd], q1 = Qb[1*KD + kd];
            float q2 = Qb[2*KD + kd], q3 = Qb[3*KD + kd];
            float q4 = Qb[4*KD + kd], q5 = Qb[5*KD + kd];
            float q6 = Qb[6*KD + kd], q7 = Qb[7*KD + kd];
            #define FMA4(A, S, KV) { A.x = fmaf((S), KV.x, A.x); A.y = fmaf((S), KV.y, A.y); \
                                     A.z = fmaf((S), KV.z, A.z); A.w = fmaf((S), KV.w, A.w); }
            FMA4(a0, q0, kva) FMA4(a1, q1, kva) FMA4(a2, q2, kva) FMA4(a3, q3, kva)
            FMA4(a4, q4, kva) FMA4(a5, q5, kva) FMA4(a6, q6, kva) FMA4(a7, q7, kva)
            FMA4(b0, q0, kvb) FMA4(b1, q1, kvb) FMA4(b2, q2, kvb) FMA4(b3, q3, kvb)
            FMA4(b4, q4, kvb) FMA4(b5, q5, kvb) FMA4(b6, q6, kvb) FMA4(b7, q7, kvb)
            #undef FMA4
        }
    }

    unsigned lm0 = 0u, lm1 = 0u, lm2 = 0u, lm3 = 0u,
             lm4 = 0u, lm5 = 0u, lm6 = 0u, lm7 = 0u;
    #define DOROW(A, R, C4, LM) { int k0,k1,k2,k3; \
        EKEY(A.x,k0); EKEY(A.y,k1); EKEY(A.z,k2); EKEY(A.w,k3); \
        LM = max(LM, (unsigned)max(max(k0,k1),max(k2,k3))); \
        ((ushort4*)ek[R])[C4] = make_ushort4((unsigned short)k0,(unsigned short)k1, \
                                             (unsigned short)k2,(unsigned short)k3); \
        atomicAdd(&h8[R][k0 >> 8], 1u); \
        atomicAdd(&h8[R][k1 >> 8], 1u); \
        atomicAdd(&h8[R][k2 >> 8], 1u); \
        atomicAdd(&h8[R][k3 >> 8], 1u); }
    DOROW(a0,0,c4a,lm0) DOROW(a1,1,c4a,lm1) DOROW(a2,2,c4a,lm2) DOROW(a3,3,c4a,lm3)
    DOROW(a4,4,c4a,lm4) DOROW(a5,5,c4a,lm5) DOROW(a6,6,c4a,lm6) DOROW(a7,7,c4a,lm7)
    DOROW(b0,0,c4b,lm0) DOROW(b1,1,c4b,lm1) DOROW(b2,2,c4b,lm2) DOROW(b3,3,c4b,lm3)
    DOROW(b4,4,c4b,lm4) DOROW(b5,5,c4b,lm5) DOROW(b6,6,c4b,lm6) DOROW(b7,7,c4b,lm7)
    #undef DOROW

    #define RMAX(V, R) { unsigned v_ = (V); \
        _Pragma("unroll") \
        for (int off = 32; off; off >>= 1) \
            v_ = max(v_, (unsigned)__shfl_down((int)v_, off, 64)); \
        if (lane == 0) redk0[wv][R] = v_; }
    RMAX(lm0,0) RMAX(lm1,1) RMAX(lm2,2) RMAX(lm3,3)
    RMAX(lm4,4) RMAX(lm5,5) RMAX(lm6,6) RMAX(lm7,7)
    #undef RMAX
    __syncthreads();                                        // B1: keys+hist+maxes

    // ================= per-wave: wave wv owns row i0+wv =====================
    const int r = wv;
    const int i = i0 + r;
    unsigned mk = 0u;
    #pragma unroll
    for (int w = 0; w < 8; ++w) mk = max(mk, redk0[w][r]);
    const ushort4* ek4 = (const ushort4*)ek[r];
    unsigned* hw = h8[r];

    #define WSCAN(RNEED, OUTB, OUTR) { \
        uint4 hh = *((const uint4*)&hw[lane << 2]); \
        unsigned s3 = hh.w, s2 = hh.w + hh.z, s1 = s2 + hh.y, s0 = s1 + hh.x; \
        unsigned X = s0; \
        _Pragma("unroll") \
        for (int off = 1; off < 64; off <<= 1) { \
            unsigned v = (unsigned)__shfl_down((int)X, off, 64); \
            if (lane + off < 64) X += v; } \
        unsigned Xn = (unsigned)__shfl_down((int)X, 1, 64); \
        if (lane == 63) Xn = 0u; \
        unsigned S0 = X, S1 = Xn + s1, S2 = Xn + s2, S3 = Xn + s3, S4 = Xn; \
        if (S0 >= (RNEED) && S1 < (RNEED)) { sh_b8[r] = (lane << 2) | 0; sh_r8[r] = (RNEED) - S1; } \
        if (S1 >= (RNEED) && S2 < (RNEED)) { sh_b8[r] = (lane << 2) | 1; sh_r8[r] = (RNEED) - S2; } \
        if (S2 >= (RNEED) && S3 < (RNEED)) { sh_b8[r] = (lane << 2) | 2; sh_r8[r] = (RNEED) - S3; } \
        if (S3 >= (RNEED) && S4 < (RNEED)) { sh_b8[r] = (lane << 2) | 3; sh_r8[r] = (RNEED) - S4; } \
        OUTB = sh_b8[r]; OUTR = sh_r8[r]; }

    // ---- pass A result: hist already built during energy ----
    unsigned bh, rn;
    WSCAN(KK, bh, rn)

    // ---- pass B: hist on low byte within selected high-byte bin ----
    #pragma unroll
    for (int z = 0; z < 4; ++z) hw[(z << 6) + lane] = 0u;
    #pragma unroll 4
    for (int g = 0; g < 16; ++g) {
        ushort4 kv = ek4[lane + (g << 6)];
        if ((unsigned)(kv.x >> 8) == bh) atomicAdd(&hw[kv.x & 255u], 1u);
        if ((unsigned)(kv.y >> 8) == bh) atomicAdd(&hw[kv.y & 255u], 1u);
        if ((unsigned)(kv.z >> 8) == bh) atomicAdd(&hw[kv.z & 255u], 1u);
        if ((unsigned)(kv.w >> 8) == bh) atomicAdd(&hw[kv.w & 255u], 1u);
    }
    unsigned bl, rt;
    WSCAN(rn, bl, rt)
    #undef WSCAN
    int tu = (int)((bh << 8) | bl);

    // ---- selection: register compaction; pack (j<<16)|bf16(w) ----
    unsigned* selw32 = hw;           // hist B dead; 409 u32 <= HSLOT
    unsigned base = 0u, tbase = 0u;
    float lsum = 0.f;
    #pragma unroll 4
    for (int g = 0; g < 16; ++g) {
        ushort4 kv = ek4[lane + (g << 6)];
        #pragma unroll
        for (int c = 0; c < 4; ++c) {
            int k = (c == 0) ? kv.x : (c == 1) ? kv.y : (c == 2) ? kv.z : kv.w;
            bool tie = (k == tu);
            unsigned long long tmask = __ballot(tie);
            bool sel = (k > tu);
            if (tie) {
                unsigned tix = tbase + (unsigned)__popcll(tmask & ((1ull << lane) - 1ull));
                sel = (tix < rt);
            }
            tbase += (unsigned)__popcll(tmask);
            unsigned long long smask = __ballot(sel);
            if (sel) {
                unsigned pos = base + (unsigned)__popcll(smask & ((1ull << lane) - 1ull));
                int j = ((lane + (g << 6)) << 2) | c;
                float w = __expf((float)(k - (int)mk) * 0.000244140625f);
                lsum += w;
                selw32[pos] = ((unsigned)j << 16) |
                              ((__float_as_uint(w) + 0x8000u) >> 16);
            }
            base += (unsigned)__popcll(smask);
        }
    }
    #pragma unroll
    for (int off = 32; off; off >>= 1) lsum += __shfl_xor(lsum, off, 64);
    float denom = lsum + EPSF;

    // ---- PV gather: 4 entries x 16 lanes x float4, one wave per row ----
    int eslot = lane >> 4, vq = lane & 15;
    const float4* Vb4 = (const float4*)(Vm + (size_t)b * NPIX * OD);
    float4 acc = make_float4(0.f, 0.f, 0.f, 0.f);
    #pragma unroll 4
    for (int s0 = 0; s0 < KK; s0 += 4) {
        int s = s0 + eslot;
        if (s < KK) {
            unsigned pk = selw32[s];
            float w = __uint_as_float(pk << 16);   // bf16 -> f32
            int j   = (int)(pk >> 16);
            float4 v4 = Vb4[(j << 4) + vq];
            acc.x = fmaf(w, v4.x, acc.x);
            acc.y = fmaf(w, v4.y, acc.y);
            acc.z = fmaf(w, v4.z, acc.z);
            acc.w = fmaf(w, v4.w, acc.w);
        }
    }
    #pragma unroll
    for (int off = 16; off <= 32; off <<= 1) {
        acc.x += __shfl_xor(acc.x, off, 64);
        acc.y += __shfl_xor(acc.y, off, 64);
        acc.z += __shfl_xor(acc.z, off, 64);
        acc.w += __shfl_xor(acc.w, off, 64);
    }
    if (lane < 16) {
        float sc = gscale / denom;
        size_t basei = ((size_t)b * CCH + (vq << 2)) * NPIX + i;
        out[basei]            = fmaf(sc, acc.x, x[basei]);
        out[basei +   NPIX]   = fmaf(sc, acc.y, x[basei +   NPIX]);
        out[basei + 2*NPIX]   = fmaf(sc, acc.z, x[basei + 2*NPIX]);
        out[basei + 3*NPIX]   = fmaf(sc, acc.w, x[basei + 3*NPIX]);
    }
}

extern "C" void kernel_launch(void* const* d_in, const int* in_sizes, int n_in,
                              void* d_out, int out_size, void* d_ws, size_t ws_size,
                              hipStream_t stream) {
    const float* x     = (const float*)d_in[0];
    const float* Wq    = (const float*)d_in[1];
    const float* bq    = (const float*)d_in[2];
    const float* Wk    = (const float*)d_in[3];
    const float* bk    = (const float*)d_in[4];
    const float* Wv    = (const float*)d_in[5];
    const float* bv    = (const float*)d_in[6];
    const float* gamma = (const float*)d_in[7];
    float* out = (float*)d_out;

    float* Q  = (float*)d_ws;
    float* Km = Q  + (size_t)BATCH * NPIX * KD;
    float* Vm = Km + (size_t)BATCH * KD * NPIX;

    qkv_kernel<<<512, 256, 0, stream>>>(x, Wq, bq, Wk, bk, Wv, bv, Q, Km, Vm);
    attn_kernel<<<BATCH * (NPIX / 8), 512, 0, stream>>>(x, Q, Km, Vm, gamma, out);
}